// Round 1
// baseline (146.057 us; speedup 1.0000x reference)
//
#include <hip/hip_runtime.h>

namespace {

constexpr int Bn = 2;
constexpr int Dn = 64;
constexpr int Hn = 96;
constexpr int Wn = 96;
constexpr int HW = Hn * Wn;          // 9216
constexpr int S  = Dn * HW;          // 589824 per (vol,batch) slab
constexpr int NBS = Bn * S;          // 1179648
constexpr int NT  = 2 * NBS;         // 2359296 (slabs: predB0,predB1,truthB0,truthB1)
constexpr int WPP = HW / 32;         // 288 words per z-plane
constexpr int WPS = S / 32;          // 18432 words per slab
constexpr int NTW = NT / 32;         // 73728 packed words
constexpr float EPSf = 1e-7f;
constexpr int BLK_SUMS = NBS / 4 / 256;   // 1152
#define BIGF 1e12f                   // RN(1e12): exact all-foreground EDT value
constexpr int LINF = 1 << 20;

// ---- K1: binarize + z-EDT: d^2 as u16 (0xFFFF=BIG) + z-L1 u8 (255=inf) ----
//      + zero-init of RMX[0..3] (rmax d2 atomics) and RMX[4] (K4 ticket)
__global__ __launch_bounds__(256) void k_bin0(const float* __restrict__ logits,
                                              const int* __restrict__ labels,
                                              unsigned short* __restrict__ FZ,
                                              unsigned char* __restrict__ DZ,
                                              unsigned* __restrict__ RMX) {
  __shared__ unsigned bits[64];
  __shared__ unsigned zlo[32], zhi[32];
  if (blockIdx.x == 0 && threadIdx.x < 8) RMX[threadIdx.x] = 0u;
  int slab = blockIdx.x / 288;                 // 1152 blocks = 4 slabs x 288 groups
  int cg = blockIdx.x - slab * 288;
  int c0 = cg * 32;
  int tid = threadIdx.x;
  int lane = tid & 63;
  for (int t = tid; t < 2048; t += 256) {
    int zz = t >> 5;
    int col = t & 31;
    int s = zz * HW + c0 + col;
    bool v;
    if (slab < 2) {
      float l0 = logits[(slab * 2 + 0) * S + s];
      float l1 = logits[(slab * 2 + 1) * S + s];
      v = l1 > l0;                             // softmax(p1)>0.5 <=> l1>l0
    } else {
      v = labels[(slab - 2) * S + s] > 0;
    }
    unsigned long long m = __ballot(v);
    if (lane == 0)       bits[zz] = (unsigned)m;
    else if (lane == 32) bits[zz] = (unsigned)(m >> 32);
  }
  __syncthreads();
  if (tid < 64) {
    int col = tid & 31;
    int base = (tid < 32) ? 0 : 32;
    unsigned zw = 0u;
    #pragma unroll
    for (int j = 0; j < 32; ++j)
      zw |= (((bits[base + j] >> col) & 1u) ^ 1u) << j;
    if (tid < 32) zlo[col] = zw; else zhi[col] = zw;
  }
  __syncthreads();
  int col = tid & 31;
  int chunk = tid >> 5;
  int i0 = chunk * 8;
  unsigned long long Z = ((unsigned long long)zhi[col] << 32) | (unsigned long long)zlo[col];
  unsigned short* o = FZ + slab * S + c0 + col;
  unsigned char* o1 = DZ + slab * S + c0 + col;
  #pragma unroll
  for (int s = 0; s < 8; ++s) {
    int i = i0 + s;
    unsigned long long below = Z & ((2ull << i) - 1ull);
    unsigned long long above = Z >> i;
    unsigned short fv;
    unsigned char dv;
    if (below | above) {
      int ddn = below ? (i - (63 - __builtin_clzll(below))) : 99;
      int dup = above ? __builtin_ctzll(above) : 99;
      int d = ddn < dup ? ddn : dup;           // <= 63
      fv = (unsigned short)(d * d);
      dv = (unsigned char)d;
    } else {
      fv = 0xFFFFu;
      dv = 255;
    }
    o[i * HW] = fv;
    o1[i * HW] = dv;
  }
}

// ---- K2: windowed exact EDT (y,x) + L1 scans, quarter-plane per block ----
// Window bound: Euclid <= L1, so only |i-j| <= L1bound candidates can win;
// all small candidates are exact ints -> integer min == reference float min.
// Block decode is XCD-chunked: xcd = blockIdx&7 carries the z-chunk so all 4
// quarters of a plane (and z-neighbors) share one XCD's L2 (round-robin %8).
// E2 output is u16 d^2 (exact: finite best <= 253^2 = 64009), 0xFFFF = BIG.
__global__ __launch_bounds__(256) void k_edtl1(const unsigned short* __restrict__ FZ,
                                               const unsigned char* __restrict__ DZ,
                                               unsigned short* __restrict__ E2,
                                               unsigned char* __restrict__ D1) {
  __shared__ __align__(16) unsigned shm[8640]; // 34560 B
  unsigned short* fz = (unsigned short*)shm;          // 9216 u16 (plane d2z)
  unsigned char*  dz = (unsigned char*)(shm + 4608);  // 9216 u8  (plane L1z)
  unsigned char*  t1 = (unsigned char*)(shm + 6912);  // 24x96 u8 (zy-L1, tile)
  unsigned short* o1 = (unsigned short*)(shm + 7488); // 24x96 u16 (pass1 out)
  unsigned short* Bv = o1;                            // bwd t1 halves (pre-pass1)
  unsigned short* Afwd = (unsigned short*)shm;        // reuse fz after pass1
  unsigned short* Bbwd = (unsigned short*)(shm + 4608); // reuse dz after t1
  int xcd = blockIdx.x & 7;
  int inner = blockIdx.x >> 3;                 // 0..127
  int q = inner & 3;
  int zoff = (inner >> 2) & 7;
  int slab = inner >> 5;                       // 0..3
  int z = xcd * 8 + zoff;
  int y0 = q * 24;
  int tid = threadIdx.x;
  int pb = slab * S + z * HW;
  // stage plane (u16 d2z + u8 L1z), fully coalesced
  {
    const uint4* s4 = (const uint4*)(FZ + pb);
    uint4* d4 = (uint4*)fz;
    for (int t = tid; t < 1152; t += 256) d4[t] = s4[t];
    const uint4* s2 = (const uint4*)(DZ + pb);
    uint4* d2 = (uint4*)(shm + 4608);
    for (int t = tid; t < 576; t += 256) d2[t] = s2[t];
  }
  __syncthreads();
  // t1[rr][xx] = min_j |y-j| + dz[j][xx]  (uncapped; 255 = inf), tile rows only.
  // Split: forward prefix on threads 0..95 (waves 0/1), backward suffix on
  // threads 128..223 (waves 2/3) concurrently; combine after barrier.
  int A[24];
  if (tid < 96) {                              // forward: A[s] = min_{j<=y}(v_j + y - j)
    int xx = tid;
    int P = LINF;
    for (int j = 0; j < y0; ++j) {
      int v = dz[j * 96 + xx]; if (v == 255) v = LINF;
      P = min(P, v - j);
    }
    #pragma unroll
    for (int s = 0; s < 24; ++s) {
      int j = y0 + s;
      int v = dz[j * 96 + xx]; if (v == 255) v = LINF;
      P = min(P, v - j);
      A[s] = j + P;
    }
  }
  if (tid >= 128 && tid < 224) {               // backward: Bv[s] = min_{j>=y}(v_j + j) - y
    int xx = tid - 128;
    int Sv = LINF;
    for (int j = 95; j >= y0; --j) {
      int v = dz[j * 96 + xx]; if (v == 255) v = LINF;
      Sv = min(Sv, v + j);
      if (j < y0 + 24) {
        int b = Sv - j;
        Bv[(j - y0) * 96 + xx] = (unsigned short)(b > 60000 ? 60000 : b);
      }
    }
  }
  __syncthreads();
  if (tid < 96) {
    int xx = tid;
    #pragma unroll
    for (int s = 0; s < 24; ++s) {
      int t = min(A[s], (int)Bv[s * 96 + xx]); // finite <= 158
      t1[s * 96 + xx] = (unsigned char)(t > 254 ? 255 : t);
    }
  }
  __syncthreads();
  // pass1 windowed: out1[y][xx] = min_{|y-j|<=t1} (y-j)^2 + fz[j][xx]
  for (int v = tid; v < 2304; v += 256) {
    int rr = v / 96;
    int xx = v - rr * 96;
    int y = y0 + rr;
    int r = t1[rr * 96 + xx];
    unsigned short res;
    if (r == 255) {
      res = 0xFFFFu;                           // whole (y,z) slice BIG -> RN(1e12)
    } else {
      int lo = y - r; if (lo < 0) lo = 0;
      int hi = y + r; if (hi > 95) hi = 95;
      int best = 1 << 30;
      for (int j = lo; j <= hi; ++j) {
        unsigned short f = fz[j * 96 + xx];
        if (f != 0xFFFFu) {
          int dd = y - j;
          best = min(best, dd * dd + (int)f);
        }
      }
      res = (unsigned short)best;              // <= t1^2 <= 24964; argmin in window
    }
    o1[rr * 96 + xx] = res;
  }
  __syncthreads();                             // fz free now
  // d1 row scans: Afwd/Bbwd halves of d1[rr][x] = min_j |x-j| + t1[rr][j]
  if (tid < 24) {                              // forward (wave 0)
    int rr = tid;
    int P = LINF;
    for (int j = 0; j < 96; ++j) {
      int v = t1[rr * 96 + j]; if (v == 255) v = LINF;
      P = min(P, v - j);
      int a = j + P;
      Afwd[rr * 96 + j] = (unsigned short)(a > 60000 ? 60000 : a);
    }
  }
  if (tid >= 64 && tid < 88) {                 // backward (wave 1)
    int rr = tid - 64;
    int Sv = LINF;
    for (int j = 95; j >= 0; --j) {
      int v = t1[rr * 96 + j]; if (v == 255) v = LINF;
      Sv = min(Sv, v + j);
      int b = Sv - j;                          // >= 0
      Bbwd[rr * 96 + j] = (unsigned short)(b > 60000 ? 60000 : b);
    }
  }
  __syncthreads();
  // pass2 windowed: E2 (u16 d^2) + capped-12 D1
  for (int v = tid; v < 2304; v += 256) {
    int rr = v / 96;
    int x = v - rr * 96;
    int d1v = min((int)Afwd[rr * 96 + x], (int)Bbwd[rr * 96 + x]);
    unsigned short oute;
    int d1c;
    if (d1v > 253) {                           // inf: whole plane BIG
      oute = 0xFFFFu;
      d1c = 12;
    } else {
      d1c = d1v < 12 ? d1v : 12;
      int lo = x - d1v; if (lo < 0) lo = 0;
      int hi = x + d1v; if (hi > 95) hi = 95;
      int best = 1 << 30;
      for (int j = lo; j <= hi; ++j) {
        unsigned short f = o1[rr * 96 + j];
        if (f != 0xFFFFu) {
          int dd = x - j;
          best = min(best, dd * dd + (int)f);
        }
      }
      oute = (unsigned short)best;             // <= d1^2 <= 64009 < 0xFFFF, exact
    }
    int gb = pb + (y0 + rr) * 96 + x;
    E2[gb] = oute;
    D1[gb] = (unsigned char)d1c;
  }
}

// ---- K3: skel = [d1 == max3x3x3(d1)] & [1<=d1<=11] + atomicMax rmax-d2 ----
__global__ __launch_bounds__(256) void k_skelmax(const unsigned char* __restrict__ D1,
                                                 const unsigned short* __restrict__ E2,
                                                 unsigned* __restrict__ SKELB,
                                                 unsigned* __restrict__ RMX) {
  __shared__ unsigned char zm[26 * 96];
  __shared__ unsigned char cen[26 * 96];
  __shared__ unsigned ldsu[4];
  int xcd = blockIdx.x & 7;
  int inner = blockIdx.x >> 3;
  int q = inner & 3;
  int zoff = (inner >> 2) & 7;
  int slab = inner >> 5;
  int z = xcd * 8 + zoff;
  int y0 = q * 24;
  int tid = threadIdx.x;
  int pb = slab * S + z * HW;
  for (int t = tid; t < 2496; t += 256) {
    int rr = t / 96;
    int x = t - rr * 96;
    int yy = y0 - 1 + rr;
    unsigned char m = 0, cv = 0;
    if (yy >= 0 && yy < Hn) {
      int base = slab * S + yy * 96 + x;
      cv = D1[base + z * HW];
      m = cv;
      if (z > 0) { unsigned char a = D1[base + (z - 1) * HW]; m = m > a ? m : a; }
      if (z < Dn - 1) { unsigned char a = D1[base + (z + 1) * HW]; m = m > a ? m : a; }
    }
    zm[t] = m;
    cen[t] = cv;
  }
  __syncthreads();
  unsigned mm = 0u;
  int wbase = slab * WPS + z * WPP + y0 * 3;
  int lane = tid & 63;
  #pragma unroll
  for (int round = 0; round < 9; ++round) {
    int v = round * 256 + tid;
    int rr = v / 96;
    int x = v - rr * 96;
    int b1 = rr * 96 + x;
    unsigned char mx = zm[b1];
    { unsigned char a = zm[b1 + 96]; mx = mx > a ? mx : a; }
    { unsigned char a = zm[b1 + 192]; mx = mx > a ? mx : a; }
    if (x > 0) {
      unsigned char a0 = zm[b1 - 1], a1 = zm[b1 + 95], a2 = zm[b1 + 191];
      unsigned char a = a0 > a1 ? a0 : a1; a = a > a2 ? a : a2;
      mx = mx > a ? mx : a;
    }
    if (x < Wn - 1) {
      unsigned char a0 = zm[b1 + 1], a1 = zm[b1 + 97], a2 = zm[b1 + 193];
      unsigned char a = a0 > a1 ? a0 : a1; a = a > a2 ? a : a2;
      mx = mx > a ? mx : a;
    }
    unsigned char d1 = cen[b1 + 96];
    bool sk = (d1 == mx) && (d1 >= 1) && (d1 <= 11);
    unsigned long long bal = __ballot(sk);
    if (lane == 0)       SKELB[wbase + (v >> 5)] = (unsigned)bal;
    else if (lane == 32) SKELB[wbase + (v >> 5)] = (unsigned)(bal >> 32);
    if (sk) {
      unsigned e = E2[pb + (y0 + rr) * 96 + x]; // finite at skel voxels
      mm = mm > e ? mm : e;
    }
  }
  #pragma unroll
  for (int o = 32; o > 0; o >>= 1) {
    unsigned t = __shfl_xor(mm, o, 64);
    mm = mm > t ? mm : t;
  }
  if (lane == 0) ldsu[tid >> 6] = mm;
  __syncthreads();
  if (tid == 0) {
    unsigned a = ldsu[0] > ldsu[1] ? ldsu[0] : ldsu[1];
    unsigned b = ldsu[2] > ldsu[3] ? ldsu[2] : ldsu[3];
    unsigned m4 = a > b ? a : b;
    if (m4 > 0u) atomicMax(RMX + slab, m4);
  }
}

// ---- K4: sums + last-block deterministic final reduce (replaces K5) ----
__global__ __launch_bounds__(256) void k_sums(const unsigned short* __restrict__ E2,
                                              const unsigned* __restrict__ skel,
                                              unsigned* __restrict__ RMX,
                                              double* __restrict__ ps,
                                              float* __restrict__ out) {
  __shared__ double ldsd[4][4];
  __shared__ int lastFlag;
  int tid = threadIdx.x;
  int q = blockIdx.x * 256 + tid;
  int idx0 = q * 4;
  int b = idx0 / S;
  float rmax_p = sqrtf((float)RMX[b]);         // max skel d2 (exact int) -> rmax
  float rmax_t = sqrtf((float)RMX[2 + b]);
  ushort4 dp4 = ((const ushort4*)E2)[q];
  ushort4 dt4 = ((const ushort4*)E2)[q + NBS / 4];
  unsigned spw = (skel[idx0 >> 5] >> (idx0 & 31)) & 0xFu;
  unsigned stw = (skel[(NBS + idx0) >> 5] >> (idx0 & 31)) & 0xFu;
  const unsigned short* dp = &dp4.x;
  const unsigned short* dt = &dt4.x;
  double acc[4] = {0.0, 0.0, 0.0, 0.0};
  #pragma unroll
  for (int s = 0; s < 4; ++s) {
    unsigned pv = dp[s];
    unsigned tv = dt[s];
    float pd2 = (pv == 0xFFFFu) ? BIGF : (float)pv;
    float td2 = (tv == 0xFFFFu) ? BIGF : (float)tv;
    float dist_p = sqrtf(pd2);
    float dist_t = sqrtf(td2);
    bool sp = (spw >> s) & 1u;
    bool st = (stw >> s) & 1u;
    float q_vp = (rmax_p > 0.0f) ? dist_p / rmax_p : dist_p;
    float q_vl = (rmax_t > 0.0f) ? dist_t / rmax_t : dist_t;
    float q_spvp = sp ? q_vp : 0.0f;
    float q_slvl = st ? q_vl : 0.0f;
    float q_sp = sp ? (1.0f + EPSf) / (q_spvp * q_spvp + EPSf) : 0.0f;
    float q_sl = st ? (1.0f + EPSf) / (q_slvl * q_slvl + EPSf) : 0.0f;
    acc[0] += (double)(q_sp * q_vl);
    acc[1] += (double)(((q_spvp != 0.0f) && (q_slvl == 0.0f)) ? q_spvp * q_sp
                                                              : q_slvl * q_sp);
    acc[2] += (double)(q_sl * q_vp);
    acc[3] += (double)(((q_slvl != 0.0f) && (q_spvp == 0.0f)) ? q_slvl * q_sl
                                                              : q_spvp * q_sl);
  }
  #pragma unroll
  for (int k = 0; k < 4; ++k)
    #pragma unroll
    for (int o = 32; o > 0; o >>= 1)
      acc[k] += __shfl_xor(acc[k], o, 64);
  if ((tid & 63) == 0) {
    #pragma unroll
    for (int k = 0; k < 4; ++k) ldsd[tid >> 6][k] = acc[k];
  }
  __syncthreads();
  if (tid == 0) {
    #pragma unroll
    for (int k = 0; k < 4; ++k)
      ps[blockIdx.x * 4 + k] = ldsd[0][k] + ldsd[1][k] + ldsd[2][k] + ldsd[3][k];
    __threadfence();                           // release ps before ticket
    unsigned old = atomicAdd(RMX + 4, 1u);     // ticket
    lastFlag = (old == (unsigned)(BLK_SUMS - 1));
  }
  __syncthreads();
  if (lastFlag) {                              // uniform per block
    __threadfence();                           // acquire other blocks' ps
    double s4[4] = {0.0, 0.0, 0.0, 0.0};
    for (int i = tid; i < BLK_SUMS; i += 256) {
      s4[0] += ps[i * 4 + 0];
      s4[1] += ps[i * 4 + 1];
      s4[2] += ps[i * 4 + 2];
      s4[3] += ps[i * 4 + 3];
    }
    #pragma unroll
    for (int k = 0; k < 4; ++k)
      #pragma unroll
      for (int o = 32; o > 0; o >>= 1)
        s4[k] += __shfl_xor(s4[k], o, 64);
    if ((tid & 63) == 0) {
      #pragma unroll
      for (int k = 0; k < 4; ++k) ldsd[tid >> 6][k] = s4[k];
    }
    __syncthreads();
    if (tid == 0) {
      double tot[4];
      #pragma unroll
      for (int k = 0; k < 4; ++k)
        tot[k] = ldsd[0][k] + ldsd[1][k] + ldsd[2][k] + ldsd[3][k];
      double wp = (tot[0] + 1.0) / (tot[1] + 1.0);
      double wsn = (tot[2] + 1.0) / (tot[3] + 1.0);
      out[0] = (float)(1.0 - 2.0 * (wp * wsn) / (wp + wsn));
    }
  }
}

} // namespace

extern "C" void kernel_launch(void* const* d_in, const int* in_sizes, int n_in,
                              void* d_out, int out_size, void* d_ws, size_t ws_size,
                              hipStream_t stream) {
  (void)in_sizes; (void)n_in; (void)out_size; (void)ws_size;
  const float* logits = (const float*)d_in[0];   // [B,2,D,H,W] f32
  const int* labels   = (const int*)d_in[1];     // [B,1,D,H,W] i32
  float* out = (float*)d_out;

  unsigned short* E2 = (unsigned short*)d_ws;      // final Euclidean d2 (u16, 0xFFFF=BIG)
  unsigned short* FZ = E2 + NT;                    // z-pass d2 (u16)
  unsigned char* DZ  = (unsigned char*)(FZ + NT);  // z-pass L1 (u8, 255=inf)
  unsigned char* D1  = DZ + NT;                    // 3D L1, capped 12 (u8)
  unsigned* SKELB = (unsigned*)(D1 + NT);          // NTW packed skel bits
  unsigned* RMX   = SKELB + NTW;                   // [0..3]=rmax d2, [4]=ticket, [5..7]=pad
  double* PS      = (double*)(RMX + 8);            // 1152x4 doubles (8B-aligned)

  k_bin0<<<1152, 256, 0, stream>>>(logits, labels, FZ, DZ, RMX);
  k_edtl1<<<1024, 256, 0, stream>>>(FZ, DZ, E2, D1);
  k_skelmax<<<1024, 256, 0, stream>>>(D1, E2, SKELB, RMX);
  k_sums<<<1152, 256, 0, stream>>>(E2, SKELB, RMX, PS, out);
}

// Round 2
// 128.796 us; speedup vs baseline: 1.1340x; 1.1340x over previous
//
#include <hip/hip_runtime.h>

namespace {

constexpr int Bn = 2;
constexpr int Dn = 64;
constexpr int Hn = 96;
constexpr int Wn = 96;
constexpr int HW = Hn * Wn;          // 9216
constexpr int S  = Dn * HW;          // 589824 per (vol,batch) slab
constexpr int NBS = Bn * S;          // 1179648
constexpr int NT  = 2 * NBS;         // 2359296 (slabs: predB0,predB1,truthB0,truthB1)
constexpr int WPP = HW / 32;         // 288 words per z-plane
constexpr int WPS = S / 32;          // 18432 words per slab
constexpr int NTW = NT / 32;         // 73728 packed words
constexpr float EPSf = 1e-7f;
constexpr int BLK_SUMS = NBS / 8 / 256;   // 576 (8 voxels per thread)
#define BIGF 1e12f                   // RN(1e12): exact all-foreground EDT value
constexpr int LINF = 1 << 20;

// ---- K1: binarize + z-EDT: d^2 as u16 (0xFFFF=BIG) + z-L1 u8 (255=inf) ----
//      + zero-init of RMX[0..3] (rmax d2 atomic targets)
__global__ __launch_bounds__(256) void k_bin0(const float* __restrict__ logits,
                                              const int* __restrict__ labels,
                                              unsigned short* __restrict__ FZ,
                                              unsigned char* __restrict__ DZ,
                                              unsigned* __restrict__ RMX) {
  __shared__ unsigned bits[64];
  __shared__ unsigned zlo[32], zhi[32];
  if (blockIdx.x == 0 && threadIdx.x < 8) RMX[threadIdx.x] = 0u;
  int slab = blockIdx.x / 288;                 // 1152 blocks = 4 slabs x 288 groups
  int cg = blockIdx.x - slab * 288;
  int c0 = cg * 32;
  int tid = threadIdx.x;
  int lane = tid & 63;
  for (int t = tid; t < 2048; t += 256) {
    int zz = t >> 5;
    int col = t & 31;
    int s = zz * HW + c0 + col;
    bool v;
    if (slab < 2) {
      float l0 = logits[(slab * 2 + 0) * S + s];
      float l1 = logits[(slab * 2 + 1) * S + s];
      v = l1 > l0;                             // softmax(p1)>0.5 <=> l1>l0
    } else {
      v = labels[(slab - 2) * S + s] > 0;
    }
    unsigned long long m = __ballot(v);
    if (lane == 0)       bits[zz] = (unsigned)m;
    else if (lane == 32) bits[zz] = (unsigned)(m >> 32);
  }
  __syncthreads();
  if (tid < 64) {
    int col = tid & 31;
    int base = (tid < 32) ? 0 : 32;
    unsigned zw = 0u;
    #pragma unroll
    for (int j = 0; j < 32; ++j)
      zw |= (((bits[base + j] >> col) & 1u) ^ 1u) << j;
    if (tid < 32) zlo[col] = zw; else zhi[col] = zw;
  }
  __syncthreads();
  int col = tid & 31;
  int chunk = tid >> 5;
  int i0 = chunk * 8;
  unsigned long long Z = ((unsigned long long)zhi[col] << 32) | (unsigned long long)zlo[col];
  unsigned short* o = FZ + slab * S + c0 + col;
  unsigned char* o1 = DZ + slab * S + c0 + col;
  #pragma unroll
  for (int s = 0; s < 8; ++s) {
    int i = i0 + s;
    unsigned long long below = Z & ((2ull << i) - 1ull);
    unsigned long long above = Z >> i;
    unsigned short fv;
    unsigned char dv;
    if (below | above) {
      int ddn = below ? (i - (63 - __builtin_clzll(below))) : 99;
      int dup = above ? __builtin_ctzll(above) : 99;
      int d = ddn < dup ? ddn : dup;           // <= 63
      fv = (unsigned short)(d * d);
      dv = (unsigned char)d;
    } else {
      fv = 0xFFFFu;
      dv = 255;
    }
    o[i * HW] = fv;
    o1[i * HW] = dv;
  }
}

// ---- K2: windowed exact EDT (y,x) + L1 scans, quarter-plane per block ----
// Window bound: Euclid <= L1, so only |i-j| <= L1bound candidates can win;
// all small candidates are exact ints -> integer min == reference float min.
// Block decode is XCD-chunked: xcd = blockIdx&7 carries the z-chunk so all 4
// quarters of a plane (and z-neighbors) share one XCD's L2 (round-robin %8).
// E2 output is u16 d^2 (exact: finite best <= 253^2 = 64009), 0xFFFF = BIG.
__global__ __launch_bounds__(256) void k_edtl1(const unsigned short* __restrict__ FZ,
                                               const unsigned char* __restrict__ DZ,
                                               unsigned short* __restrict__ E2,
                                               unsigned char* __restrict__ D1) {
  __shared__ __align__(16) unsigned shm[8640]; // 34560 B
  unsigned short* fz = (unsigned short*)shm;          // 9216 u16 (plane d2z)
  unsigned char*  dz = (unsigned char*)(shm + 4608);  // 9216 u8  (plane L1z)
  unsigned char*  t1 = (unsigned char*)(shm + 6912);  // 24x96 u8 (zy-L1, tile)
  unsigned short* o1 = (unsigned short*)(shm + 7488); // 24x96 u16 (pass1 out)
  unsigned short* Bv = o1;                            // bwd t1 halves (pre-pass1)
  unsigned short* Afwd = (unsigned short*)shm;        // reuse fz after pass1
  unsigned short* Bbwd = (unsigned short*)(shm + 4608); // reuse dz after t1
  int xcd = blockIdx.x & 7;
  int inner = blockIdx.x >> 3;                 // 0..127
  int q = inner & 3;
  int zoff = (inner >> 2) & 7;
  int slab = inner >> 5;                       // 0..3
  int z = xcd * 8 + zoff;
  int y0 = q * 24;
  int tid = threadIdx.x;
  int pb = slab * S + z * HW;
  // stage plane (u16 d2z + u8 L1z), fully coalesced
  {
    const uint4* s4 = (const uint4*)(FZ + pb);
    uint4* d4 = (uint4*)fz;
    for (int t = tid; t < 1152; t += 256) d4[t] = s4[t];
    const uint4* s2 = (const uint4*)(DZ + pb);
    uint4* d2 = (uint4*)(shm + 4608);
    for (int t = tid; t < 576; t += 256) d2[t] = s2[t];
  }
  __syncthreads();
  // t1[rr][xx] = min_j |y-j| + dz[j][xx]  (uncapped; 255 = inf), tile rows only.
  // Split: forward prefix on threads 0..95 (waves 0/1), backward suffix on
  // threads 128..223 (waves 2/3) concurrently; combine after barrier.
  int A[24];
  if (tid < 96) {                              // forward: A[s] = min_{j<=y}(v_j + y - j)
    int xx = tid;
    int P = LINF;
    for (int j = 0; j < y0; ++j) {
      int v = dz[j * 96 + xx]; if (v == 255) v = LINF;
      P = min(P, v - j);
    }
    #pragma unroll
    for (int s = 0; s < 24; ++s) {
      int j = y0 + s;
      int v = dz[j * 96 + xx]; if (v == 255) v = LINF;
      P = min(P, v - j);
      A[s] = j + P;
    }
  }
  if (tid >= 128 && tid < 224) {               // backward: Bv[s] = min_{j>=y}(v_j + j) - y
    int xx = tid - 128;
    int Sv = LINF;
    for (int j = 95; j >= y0; --j) {
      int v = dz[j * 96 + xx]; if (v == 255) v = LINF;
      Sv = min(Sv, v + j);
      if (j < y0 + 24) {
        int b = Sv - j;
        Bv[(j - y0) * 96 + xx] = (unsigned short)(b > 60000 ? 60000 : b);
      }
    }
  }
  __syncthreads();
  if (tid < 96) {
    int xx = tid;
    #pragma unroll
    for (int s = 0; s < 24; ++s) {
      int t = min(A[s], (int)Bv[s * 96 + xx]); // finite <= 158
      t1[s * 96 + xx] = (unsigned char)(t > 254 ? 255 : t);
    }
  }
  __syncthreads();
  // pass1 windowed: out1[y][xx] = min_{|y-j|<=t1} (y-j)^2 + fz[j][xx]
  for (int v = tid; v < 2304; v += 256) {
    int rr = v / 96;
    int xx = v - rr * 96;
    int y = y0 + rr;
    int r = t1[rr * 96 + xx];
    unsigned short res;
    if (r == 255) {
      res = 0xFFFFu;                           // whole (y,z) slice BIG -> RN(1e12)
    } else {
      int lo = y - r; if (lo < 0) lo = 0;
      int hi = y + r; if (hi > 95) hi = 95;
      int best = 1 << 30;
      for (int j = lo; j <= hi; ++j) {
        unsigned short f = fz[j * 96 + xx];
        if (f != 0xFFFFu) {
          int dd = y - j;
          best = min(best, dd * dd + (int)f);
        }
      }
      res = (unsigned short)best;              // <= t1^2 <= 24964; argmin in window
    }
    o1[rr * 96 + xx] = res;
  }
  __syncthreads();                             // fz free now
  // d1 row scans: Afwd/Bbwd halves of d1[rr][x] = min_j |x-j| + t1[rr][j]
  if (tid < 24) {                              // forward (wave 0)
    int rr = tid;
    int P = LINF;
    for (int j = 0; j < 96; ++j) {
      int v = t1[rr * 96 + j]; if (v == 255) v = LINF;
      P = min(P, v - j);
      int a = j + P;
      Afwd[rr * 96 + j] = (unsigned short)(a > 60000 ? 60000 : a);
    }
  }
  if (tid >= 64 && tid < 88) {                 // backward (wave 1)
    int rr = tid - 64;
    int Sv = LINF;
    for (int j = 95; j >= 0; --j) {
      int v = t1[rr * 96 + j]; if (v == 255) v = LINF;
      Sv = min(Sv, v + j);
      int b = Sv - j;                          // >= 0
      Bbwd[rr * 96 + j] = (unsigned short)(b > 60000 ? 60000 : b);
    }
  }
  __syncthreads();
  // pass2 windowed: E2 (u16 d^2) + capped-12 D1
  for (int v = tid; v < 2304; v += 256) {
    int rr = v / 96;
    int x = v - rr * 96;
    int d1v = min((int)Afwd[rr * 96 + x], (int)Bbwd[rr * 96 + x]);
    unsigned short oute;
    int d1c;
    if (d1v > 253) {                           // inf: whole plane BIG
      oute = 0xFFFFu;
      d1c = 12;
    } else {
      d1c = d1v < 12 ? d1v : 12;
      int lo = x - d1v; if (lo < 0) lo = 0;
      int hi = x + d1v; if (hi > 95) hi = 95;
      int best = 1 << 30;
      for (int j = lo; j <= hi; ++j) {
        unsigned short f = o1[rr * 96 + j];
        if (f != 0xFFFFu) {
          int dd = x - j;
          best = min(best, dd * dd + (int)f);
        }
      }
      oute = (unsigned short)best;             // <= d1^2 <= 64009 < 0xFFFF, exact
    }
    int gb = pb + (y0 + rr) * 96 + x;
    E2[gb] = oute;
    D1[gb] = (unsigned char)d1c;
  }
}

// ---- K3: skel = [d1 == max3x3x3(d1)] & [1<=d1<=11] + atomicMax rmax-d2 ----
__global__ __launch_bounds__(256) void k_skelmax(const unsigned char* __restrict__ D1,
                                                 const unsigned short* __restrict__ E2,
                                                 unsigned* __restrict__ SKELB,
                                                 unsigned* __restrict__ RMX) {
  __shared__ unsigned char zm[26 * 96];
  __shared__ unsigned char cen[26 * 96];
  __shared__ unsigned ldsu[4];
  int xcd = blockIdx.x & 7;
  int inner = blockIdx.x >> 3;
  int q = inner & 3;
  int zoff = (inner >> 2) & 7;
  int slab = inner >> 5;
  int z = xcd * 8 + zoff;
  int y0 = q * 24;
  int tid = threadIdx.x;
  int pb = slab * S + z * HW;
  for (int t = tid; t < 2496; t += 256) {
    int rr = t / 96;
    int x = t - rr * 96;
    int yy = y0 - 1 + rr;
    unsigned char m = 0, cv = 0;
    if (yy >= 0 && yy < Hn) {
      int base = slab * S + yy * 96 + x;
      cv = D1[base + z * HW];
      m = cv;
      if (z > 0) { unsigned char a = D1[base + (z - 1) * HW]; m = m > a ? m : a; }
      if (z < Dn - 1) { unsigned char a = D1[base + (z + 1) * HW]; m = m > a ? m : a; }
    }
    zm[t] = m;
    cen[t] = cv;
  }
  __syncthreads();
  unsigned mm = 0u;
  int wbase = slab * WPS + z * WPP + y0 * 3;
  int lane = tid & 63;
  #pragma unroll
  for (int round = 0; round < 9; ++round) {
    int v = round * 256 + tid;
    int rr = v / 96;
    int x = v - rr * 96;
    int b1 = rr * 96 + x;
    unsigned char mx = zm[b1];
    { unsigned char a = zm[b1 + 96]; mx = mx > a ? mx : a; }
    { unsigned char a = zm[b1 + 192]; mx = mx > a ? mx : a; }
    if (x > 0) {
      unsigned char a0 = zm[b1 - 1], a1 = zm[b1 + 95], a2 = zm[b1 + 191];
      unsigned char a = a0 > a1 ? a0 : a1; a = a > a2 ? a : a2;
      mx = mx > a ? mx : a;
    }
    if (x < Wn - 1) {
      unsigned char a0 = zm[b1 + 1], a1 = zm[b1 + 97], a2 = zm[b1 + 193];
      unsigned char a = a0 > a1 ? a0 : a1; a = a > a2 ? a : a2;
      mx = mx > a ? mx : a;
    }
    unsigned char d1 = cen[b1 + 96];
    bool sk = (d1 == mx) && (d1 >= 1) && (d1 <= 11);
    unsigned long long bal = __ballot(sk);
    if (lane == 0)       SKELB[wbase + (v >> 5)] = (unsigned)bal;
    else if (lane == 32) SKELB[wbase + (v >> 5)] = (unsigned)(bal >> 32);
    if (sk) {
      unsigned e = E2[pb + (y0 + rr) * 96 + x]; // finite at skel voxels
      mm = mm > e ? mm : e;
    }
  }
  #pragma unroll
  for (int o = 32; o > 0; o >>= 1) {
    unsigned t = __shfl_xor(mm, o, 64);
    mm = mm > t ? mm : t;
  }
  if (lane == 0) ldsu[tid >> 6] = mm;
  __syncthreads();
  if (tid == 0) {
    unsigned a = ldsu[0] > ldsu[1] ? ldsu[0] : ldsu[1];
    unsigned b = ldsu[2] > ldsu[3] ? ldsu[2] : ldsu[3];
    unsigned m4 = a > b ? a : b;
    if (m4 > 0u) atomicMax(RMX + slab, m4);
  }
}

// ---- K4: sums, 8 voxels/thread (576 blocks), plain partial stores ----
__global__ __launch_bounds__(256) void k_sums(const unsigned short* __restrict__ E2,
                                              const unsigned* __restrict__ skel,
                                              const unsigned* __restrict__ RMX,
                                              double* __restrict__ ps) {
  __shared__ double ldsd[4][4];
  int tid = threadIdx.x;
  int q = blockIdx.x * 256 + tid;
  int idx0 = q * 8;
  int b = idx0 / S;
  float rmax_p = sqrtf((float)RMX[b]);         // max skel d2 (exact int) -> rmax
  float rmax_t = sqrtf((float)RMX[2 + b]);
  uint4 dp4 = ((const uint4*)E2)[q];
  uint4 dt4 = ((const uint4*)E2)[q + NBS / 8];
  unsigned spw = (skel[idx0 >> 5] >> (idx0 & 31)) & 0xFFu;
  unsigned stw = (skel[(NBS + idx0) >> 5] >> (idx0 & 31)) & 0xFFu;
  const unsigned short* dp = (const unsigned short*)&dp4;
  const unsigned short* dt = (const unsigned short*)&dt4;
  double acc[4] = {0.0, 0.0, 0.0, 0.0};
  #pragma unroll
  for (int s = 0; s < 8; ++s) {
    unsigned pv = dp[s];
    unsigned tv = dt[s];
    float pd2 = (pv == 0xFFFFu) ? BIGF : (float)pv;
    float td2 = (tv == 0xFFFFu) ? BIGF : (float)tv;
    float dist_p = sqrtf(pd2);
    float dist_t = sqrtf(td2);
    bool sp = (spw >> s) & 1u;
    bool st = (stw >> s) & 1u;
    float q_vp = (rmax_p > 0.0f) ? dist_p / rmax_p : dist_p;
    float q_vl = (rmax_t > 0.0f) ? dist_t / rmax_t : dist_t;
    float q_spvp = sp ? q_vp : 0.0f;
    float q_slvl = st ? q_vl : 0.0f;
    float q_sp = sp ? (1.0f + EPSf) / (q_spvp * q_spvp + EPSf) : 0.0f;
    float q_sl = st ? (1.0f + EPSf) / (q_slvl * q_slvl + EPSf) : 0.0f;
    acc[0] += (double)(q_sp * q_vl);
    acc[1] += (double)(((q_spvp != 0.0f) && (q_slvl == 0.0f)) ? q_spvp * q_sp
                                                              : q_slvl * q_sp);
    acc[2] += (double)(q_sl * q_vp);
    acc[3] += (double)(((q_slvl != 0.0f) && (q_spvp == 0.0f)) ? q_slvl * q_sl
                                                              : q_spvp * q_sl);
  }
  #pragma unroll
  for (int k = 0; k < 4; ++k)
    #pragma unroll
    for (int o = 32; o > 0; o >>= 1)
      acc[k] += __shfl_xor(acc[k], o, 64);
  if ((tid & 63) == 0) {
    #pragma unroll
    for (int k = 0; k < 4; ++k) ldsd[tid >> 6][k] = acc[k];
  }
  __syncthreads();
  if (tid == 0) {
    #pragma unroll
    for (int k = 0; k < 4; ++k)
      ps[blockIdx.x * 4 + k] = ldsd[0][k] + ldsd[1][k] + ldsd[2][k] + ldsd[3][k];
  }
}

// ---- K5: final reduce + loss ----
__global__ __launch_bounds__(256) void k_final(const double* __restrict__ ps,
                                               float* __restrict__ out) {
  __shared__ double ldsd[4][4];
  int tid = threadIdx.x;
  double s[4] = {0.0, 0.0, 0.0, 0.0};
  for (int i = tid; i < BLK_SUMS; i += 256) {
    s[0] += ps[i * 4 + 0];
    s[1] += ps[i * 4 + 1];
    s[2] += ps[i * 4 + 2];
    s[3] += ps[i * 4 + 3];
  }
  #pragma unroll
  for (int k = 0; k < 4; ++k)
    #pragma unroll
    for (int o = 32; o > 0; o >>= 1)
      s[k] += __shfl_xor(s[k], o, 64);
  if ((tid & 63) == 0) {
    #pragma unroll
    for (int k = 0; k < 4; ++k) ldsd[tid >> 6][k] = s[k];
  }
  __syncthreads();
  if (tid == 0) {
    double tot[4];
    #pragma unroll
    for (int k = 0; k < 4; ++k)
      tot[k] = ldsd[0][k] + ldsd[1][k] + ldsd[2][k] + ldsd[3][k];
    double wp = (tot[0] + 1.0) / (tot[1] + 1.0);
    double ws = (tot[2] + 1.0) / (tot[3] + 1.0);
    out[0] = (float)(1.0 - 2.0 * (wp * ws) / (wp + ws));
  }
}

} // namespace

extern "C" void kernel_launch(void* const* d_in, const int* in_sizes, int n_in,
                              void* d_out, int out_size, void* d_ws, size_t ws_size,
                              hipStream_t stream) {
  (void)in_sizes; (void)n_in; (void)out_size; (void)ws_size;
  const float* logits = (const float*)d_in[0];   // [B,2,D,H,W] f32
  const int* labels   = (const int*)d_in[1];     // [B,1,D,H,W] i32
  float* out = (float*)d_out;

  unsigned short* E2 = (unsigned short*)d_ws;      // final Euclidean d2 (u16, 0xFFFF=BIG)
  unsigned short* FZ = E2 + NT;                    // z-pass d2 (u16)
  unsigned char* DZ  = (unsigned char*)(FZ + NT);  // z-pass L1 (u8, 255=inf)
  unsigned char* D1  = DZ + NT;                    // 3D L1, capped 12 (u8)
  unsigned* SKELB = (unsigned*)(D1 + NT);          // NTW packed skel bits
  unsigned* RMX   = SKELB + NTW;                   // [0..3]=rmax d2, [4..7]=pad
  double* PS      = (double*)(RMX + 8);            // 576x4 doubles (8B-aligned)

  k_bin0<<<1152, 256, 0, stream>>>(logits, labels, FZ, DZ, RMX);
  k_edtl1<<<1024, 256, 0, stream>>>(FZ, DZ, E2, D1);
  k_skelmax<<<1024, 256, 0, stream>>>(D1, E2, SKELB, RMX);
  k_sums<<<576, 256, 0, stream>>>(E2, SKELB, RMX, PS);
  k_final<<<1, 256, 0, stream>>>(PS, out);
}

// Round 3
// 123.612 us; speedup vs baseline: 1.1816x; 1.0419x over previous
//
#include <hip/hip_runtime.h>

namespace {

constexpr int Bn = 2;
constexpr int Dn = 64;
constexpr int Hn = 96;
constexpr int Wn = 96;
constexpr int HW = Hn * Wn;          // 9216
constexpr int S  = Dn * HW;          // 589824 per (vol,batch) slab
constexpr int NBS = Bn * S;          // 1179648
constexpr int NT  = 2 * NBS;         // 2359296 (slabs: predB0,predB1,truthB0,truthB1)
constexpr int WPP = HW / 32;         // 288 words per z-plane
constexpr int WPS = S / 32;          // 18432 words per slab
constexpr int NTW = NT / 32;         // 73728 packed words
constexpr float EPSf = 1e-7f;
constexpr int BLK_SUMS = NBS / 8 / 256;   // 576 (8 voxels per thread)
#define BIGF 1e12f                   // RN(1e12): exact all-foreground EDT value
constexpr int LINF = 1 << 20;

// ---- K1: binarize + z-EDT: d^2 as u16 (0xFFFF=BIG) + z-L1 u8 (255=inf) ----
__global__ __launch_bounds__(256) void k_bin0(const float* __restrict__ logits,
                                              const int* __restrict__ labels,
                                              unsigned short* __restrict__ FZ,
                                              unsigned char* __restrict__ DZ) {
  __shared__ unsigned bits[64];
  __shared__ unsigned zlo[32], zhi[32];
  int slab = blockIdx.x / 288;                 // 1152 blocks = 4 slabs x 288 groups
  int cg = blockIdx.x - slab * 288;
  int c0 = cg * 32;
  int tid = threadIdx.x;
  int lane = tid & 63;
  for (int t = tid; t < 2048; t += 256) {
    int zz = t >> 5;
    int col = t & 31;
    int s = zz * HW + c0 + col;
    bool v;
    if (slab < 2) {
      float l0 = logits[(slab * 2 + 0) * S + s];
      float l1 = logits[(slab * 2 + 1) * S + s];
      v = l1 > l0;                             // softmax(p1)>0.5 <=> l1>l0
    } else {
      v = labels[(slab - 2) * S + s] > 0;
    }
    unsigned long long m = __ballot(v);
    if (lane == 0)       bits[zz] = (unsigned)m;
    else if (lane == 32) bits[zz] = (unsigned)(m >> 32);
  }
  __syncthreads();
  if (tid < 64) {
    int col = tid & 31;
    int base = (tid < 32) ? 0 : 32;
    unsigned zw = 0u;
    #pragma unroll
    for (int j = 0; j < 32; ++j)
      zw |= (((bits[base + j] >> col) & 1u) ^ 1u) << j;
    if (tid < 32) zlo[col] = zw; else zhi[col] = zw;
  }
  __syncthreads();
  int col = tid & 31;
  int chunk = tid >> 5;
  int i0 = chunk * 8;
  unsigned long long Z = ((unsigned long long)zhi[col] << 32) | (unsigned long long)zlo[col];
  unsigned short* o = FZ + slab * S + c0 + col;
  unsigned char* o1 = DZ + slab * S + c0 + col;
  #pragma unroll
  for (int s = 0; s < 8; ++s) {
    int i = i0 + s;
    unsigned long long below = Z & ((2ull << i) - 1ull);
    unsigned long long above = Z >> i;
    unsigned short fv;
    unsigned char dv;
    if (below | above) {
      int ddn = below ? (i - (63 - __builtin_clzll(below))) : 99;
      int dup = above ? __builtin_ctzll(above) : 99;
      int d = ddn < dup ? ddn : dup;           // <= 63
      fv = (unsigned short)(d * d);
      dv = (unsigned char)d;
    } else {
      fv = 0xFFFFu;
      dv = 255;
    }
    o[i * HW] = fv;
    o1[i * HW] = dv;
  }
}

// ---- K2: windowed exact EDT (y,x) + L1 scans, quarter-plane per block ----
// Window bound: Euclid <= L1, so only |i-j| <= L1bound candidates can win;
// all small candidates are exact ints -> integer min == reference float min.
// E2 output is u16 d^2 (exact: finite best <= 253^2 = 64009), 0xFFFF = BIG.
__global__ __launch_bounds__(256) void k_edtl1(const unsigned short* __restrict__ FZ,
                                               const unsigned char* __restrict__ DZ,
                                               unsigned short* __restrict__ E2,
                                               unsigned char* __restrict__ D1) {
  __shared__ __align__(16) unsigned shm[8640]; // 34560 B
  unsigned short* fz = (unsigned short*)shm;          // 9216 u16 (plane d2z)
  unsigned char*  dz = (unsigned char*)(shm + 4608);  // 9216 u8  (plane L1z)
  unsigned char*  t1 = (unsigned char*)(shm + 6912);  // 24x96 u8 (zy-L1, tile)
  unsigned short* o1 = (unsigned short*)(shm + 7488); // 24x96 u16 (pass1 out)
  unsigned short* Bv = o1;                            // bwd t1 halves (pre-pass1)
  unsigned short* Afwd = (unsigned short*)shm;        // reuse fz after pass1
  unsigned short* Bbwd = (unsigned short*)(shm + 4608); // reuse dz after t1
  int slab = blockIdx.x >> 8;                  // 1024 = slab(4) x z(64) x q(4)
  int z = (blockIdx.x >> 2) & 63;
  int y0 = (blockIdx.x & 3) * 24;
  int tid = threadIdx.x;
  int pb = slab * S + z * HW;
  // stage plane (u16 d2z + u8 L1z), fully coalesced
  {
    const uint4* s4 = (const uint4*)(FZ + pb);
    uint4* d4 = (uint4*)fz;
    for (int t = tid; t < 1152; t += 256) d4[t] = s4[t];
    const uint4* s2 = (const uint4*)(DZ + pb);
    uint4* d2 = (uint4*)(shm + 4608);
    for (int t = tid; t < 576; t += 256) d2[t] = s2[t];
  }
  __syncthreads();
  // t1[rr][xx] = min_j |y-j| + dz[j][xx]  (uncapped; 255 = inf), tile rows only.
  // Split: forward prefix on threads 0..95 (waves 0/1), backward suffix on
  // threads 128..223 (waves 2/3) concurrently; combine after barrier.
  int A[24];
  if (tid < 96) {                              // forward: A[s] = min_{j<=y}(v_j + y - j)
    int xx = tid;
    int P = LINF;
    for (int j = 0; j < y0; ++j) {
      int v = dz[j * 96 + xx]; if (v == 255) v = LINF;
      P = min(P, v - j);
    }
    #pragma unroll
    for (int s = 0; s < 24; ++s) {
      int j = y0 + s;
      int v = dz[j * 96 + xx]; if (v == 255) v = LINF;
      P = min(P, v - j);
      A[s] = j + P;
    }
  }
  if (tid >= 128 && tid < 224) {               // backward: Bv[s] = min_{j>=y}(v_j + j) - y
    int xx = tid - 128;
    int Sv = LINF;
    for (int j = 95; j >= y0; --j) {
      int v = dz[j * 96 + xx]; if (v == 255) v = LINF;
      Sv = min(Sv, v + j);
      if (j < y0 + 24) {
        int b = Sv - j;
        Bv[(j - y0) * 96 + xx] = (unsigned short)(b > 60000 ? 60000 : b);
      }
    }
  }
  __syncthreads();
  if (tid < 96) {
    int xx = tid;
    #pragma unroll
    for (int s = 0; s < 24; ++s) {
      int t = min(A[s], (int)Bv[s * 96 + xx]); // finite <= 158
      t1[s * 96 + xx] = (unsigned char)(t > 254 ? 255 : t);
    }
  }
  __syncthreads();
  // pass1 windowed: out1[y][xx] = min_{|y-j|<=t1} (y-j)^2 + fz[j][xx]
  for (int v = tid; v < 2304; v += 256) {
    int rr = v / 96;
    int xx = v - rr * 96;
    int y = y0 + rr;
    int r = t1[rr * 96 + xx];
    unsigned short res;
    if (r == 255) {
      res = 0xFFFFu;                           // whole (y,z) slice BIG -> RN(1e12)
    } else {
      int lo = y - r; if (lo < 0) lo = 0;
      int hi = y + r; if (hi > 95) hi = 95;
      int best = 1 << 30;
      for (int j = lo; j <= hi; ++j) {
        unsigned short f = fz[j * 96 + xx];
        if (f != 0xFFFFu) {
          int dd = y - j;
          best = min(best, dd * dd + (int)f);
        }
      }
      res = (unsigned short)best;              // <= t1^2 <= 24964; argmin in window
    }
    o1[rr * 96 + xx] = res;
  }
  __syncthreads();                             // fz free now
  // d1 row scans: Afwd/Bbwd halves of d1[rr][x] = min_j |x-j| + t1[rr][j]
  if (tid < 24) {                              // forward (wave 0)
    int rr = tid;
    int P = LINF;
    for (int j = 0; j < 96; ++j) {
      int v = t1[rr * 96 + j]; if (v == 255) v = LINF;
      P = min(P, v - j);
      int a = j + P;
      Afwd[rr * 96 + j] = (unsigned short)(a > 60000 ? 60000 : a);
    }
  }
  if (tid >= 64 && tid < 88) {                 // backward (wave 1)
    int rr = tid - 64;
    int Sv = LINF;
    for (int j = 95; j >= 0; --j) {
      int v = t1[rr * 96 + j]; if (v == 255) v = LINF;
      Sv = min(Sv, v + j);
      int b = Sv - j;                          // >= 0
      Bbwd[rr * 96 + j] = (unsigned short)(b > 60000 ? 60000 : b);
    }
  }
  __syncthreads();
  // pass2 windowed: E2 (u16 d^2) + capped-12 D1
  for (int v = tid; v < 2304; v += 256) {
    int rr = v / 96;
    int x = v - rr * 96;
    int d1v = min((int)Afwd[rr * 96 + x], (int)Bbwd[rr * 96 + x]);
    unsigned short oute;
    int d1c;
    if (d1v > 253) {                           // inf: whole plane BIG
      oute = 0xFFFFu;
      d1c = 12;
    } else {
      d1c = d1v < 12 ? d1v : 12;
      int lo = x - d1v; if (lo < 0) lo = 0;
      int hi = x + d1v; if (hi > 95) hi = 95;
      int best = 1 << 30;
      for (int j = lo; j <= hi; ++j) {
        unsigned short f = o1[rr * 96 + j];
        if (f != 0xFFFFu) {
          int dd = x - j;
          best = min(best, dd * dd + (int)f);
        }
      }
      oute = (unsigned short)best;             // <= d1^2 <= 64009 < 0xFFFF, exact
    }
    int gb = pb + (y0 + rr) * 96 + x;
    E2[gb] = oute;
    D1[gb] = (unsigned char)d1c;
  }
}

// ---- K3: skel = [d1 == max3x3x3(d1)] & [1<=d1<=11] + masked per-block max d2 ----
__global__ __launch_bounds__(256) void k_skelmax(const unsigned char* __restrict__ D1,
                                                 const unsigned short* __restrict__ E2,
                                                 unsigned* __restrict__ SKELB,
                                                 unsigned* __restrict__ pmax) {
  __shared__ unsigned char zm[26 * 96];
  __shared__ unsigned char cen[26 * 96];
  __shared__ unsigned ldsu[4];
  int slab = blockIdx.x >> 8;
  int z = (blockIdx.x >> 2) & 63;
  int y0 = (blockIdx.x & 3) * 24;
  int tid = threadIdx.x;
  int pb = slab * S + z * HW;
  for (int t = tid; t < 2496; t += 256) {
    int rr = t / 96;
    int x = t - rr * 96;
    int yy = y0 - 1 + rr;
    unsigned char m = 0, cv = 0;
    if (yy >= 0 && yy < Hn) {
      int base = slab * S + yy * 96 + x;
      cv = D1[base + z * HW];
      m = cv;
      if (z > 0) { unsigned char a = D1[base + (z - 1) * HW]; m = m > a ? m : a; }
      if (z < Dn - 1) { unsigned char a = D1[base + (z + 1) * HW]; m = m > a ? m : a; }
    }
    zm[t] = m;
    cen[t] = cv;
  }
  __syncthreads();
  unsigned mm = 0u;
  int wbase = slab * WPS + z * WPP + y0 * 3;
  int lane = tid & 63;
  #pragma unroll
  for (int round = 0; round < 9; ++round) {
    int v = round * 256 + tid;
    int rr = v / 96;
    int x = v - rr * 96;
    int b1 = rr * 96 + x;
    unsigned char mx = zm[b1];
    { unsigned char a = zm[b1 + 96]; mx = mx > a ? mx : a; }
    { unsigned char a = zm[b1 + 192]; mx = mx > a ? mx : a; }
    if (x > 0) {
      unsigned char a0 = zm[b1 - 1], a1 = zm[b1 + 95], a2 = zm[b1 + 191];
      unsigned char a = a0 > a1 ? a0 : a1; a = a > a2 ? a : a2;
      mx = mx > a ? mx : a;
    }
    if (x < Wn - 1) {
      unsigned char a0 = zm[b1 + 1], a1 = zm[b1 + 97], a2 = zm[b1 + 193];
      unsigned char a = a0 > a1 ? a0 : a1; a = a > a2 ? a : a2;
      mx = mx > a ? mx : a;
    }
    unsigned char d1 = cen[b1 + 96];
    bool sk = (d1 == mx) && (d1 >= 1) && (d1 <= 11);
    unsigned long long bal = __ballot(sk);
    if (lane == 0)       SKELB[wbase + (v >> 5)] = (unsigned)bal;
    else if (lane == 32) SKELB[wbase + (v >> 5)] = (unsigned)(bal >> 32);
    if (sk) {
      unsigned e = E2[pb + (y0 + rr) * 96 + x]; // finite at skel voxels
      mm = mm > e ? mm : e;
    }
  }
  #pragma unroll
  for (int o = 32; o > 0; o >>= 1) {
    unsigned t = __shfl_xor(mm, o, 64);
    mm = mm > t ? mm : t;
  }
  if (lane == 0) ldsu[tid >> 6] = mm;
  __syncthreads();
  if (tid == 0) {
    unsigned a = ldsu[0] > ldsu[1] ? ldsu[0] : ldsu[1];
    unsigned b = ldsu[2] > ldsu[3] ? ldsu[2] : ldsu[3];
    pmax[blockIdx.x] = a > b ? a : b;
  }
}

// ---- K4: sums, 8 voxels/thread (576 blocks), plain partial stores ----
__global__ __launch_bounds__(256) void k_sums(const unsigned short* __restrict__ E2,
                                              const unsigned* __restrict__ skel,
                                              const unsigned* __restrict__ pmax,
                                              double* __restrict__ ps) {
  __shared__ unsigned lmax[4];
  __shared__ double ldsd[4][4];
  int tid = threadIdx.x;
  {
    int wave = tid >> 6, lane = tid & 63;
    const unsigned* pw = pmax + wave * 256;
    unsigned v = pw[lane];
    { unsigned a = pw[lane + 64];  v = v > a ? v : a; }
    { unsigned a = pw[lane + 128]; v = v > a ? v : a; }
    { unsigned a = pw[lane + 192]; v = v > a ? v : a; }
    #pragma unroll
    for (int o = 32; o > 0; o >>= 1) {
      unsigned t = __shfl_xor(v, o, 64);
      v = v > t ? v : t;
    }
    if (lane == 0) lmax[wave] = v;
  }
  __syncthreads();
  int q = blockIdx.x * 256 + tid;
  int idx0 = q * 8;
  int b = idx0 / S;
  float rmax_p = sqrtf((float)lmax[b]);        // max skel d2 (exact int) -> rmax
  float rmax_t = sqrtf((float)lmax[2 + b]);
  uint4 dp4 = ((const uint4*)E2)[q];
  uint4 dt4 = ((const uint4*)E2)[q + NBS / 8];
  unsigned spw = (skel[idx0 >> 5] >> (idx0 & 31)) & 0xFFu;
  unsigned stw = (skel[(NBS + idx0) >> 5] >> (idx0 & 31)) & 0xFFu;
  const unsigned short* dp = (const unsigned short*)&dp4;
  const unsigned short* dt = (const unsigned short*)&dt4;
  double acc[4] = {0.0, 0.0, 0.0, 0.0};
  #pragma unroll
  for (int s = 0; s < 8; ++s) {
    unsigned pv = dp[s];
    unsigned tv = dt[s];
    float pd2 = (pv == 0xFFFFu) ? BIGF : (float)pv;
    float td2 = (tv == 0xFFFFu) ? BIGF : (float)tv;
    float dist_p = sqrtf(pd2);
    float dist_t = sqrtf(td2);
    bool sp = (spw >> s) & 1u;
    bool st = (stw >> s) & 1u;
    float q_vp = (rmax_p > 0.0f) ? dist_p / rmax_p : dist_p;
    float q_vl = (rmax_t > 0.0f) ? dist_t / rmax_t : dist_t;
    float q_spvp = sp ? q_vp : 0.0f;
    float q_slvl = st ? q_vl : 0.0f;
    float q_sp = sp ? (1.0f + EPSf) / (q_spvp * q_spvp + EPSf) : 0.0f;
    float q_sl = st ? (1.0f + EPSf) / (q_slvl * q_slvl + EPSf) : 0.0f;
    acc[0] += (double)(q_sp * q_vl);
    acc[1] += (double)(((q_spvp != 0.0f) && (q_slvl == 0.0f)) ? q_spvp * q_sp
                                                              : q_slvl * q_sp);
    acc[2] += (double)(q_sl * q_vp);
    acc[3] += (double)(((q_slvl != 0.0f) && (q_spvp == 0.0f)) ? q_slvl * q_sl
                                                              : q_spvp * q_sl);
  }
  #pragma unroll
  for (int k = 0; k < 4; ++k)
    #pragma unroll
    for (int o = 32; o > 0; o >>= 1)
      acc[k] += __shfl_xor(acc[k], o, 64);
  if ((tid & 63) == 0) {
    #pragma unroll
    for (int k = 0; k < 4; ++k) ldsd[tid >> 6][k] = acc[k];
  }
  __syncthreads();
  if (tid == 0) {
    #pragma unroll
    for (int k = 0; k < 4; ++k)
      ps[blockIdx.x * 4 + k] = ldsd[0][k] + ldsd[1][k] + ldsd[2][k] + ldsd[3][k];
  }
}

// ---- K5: final reduce + loss ----
__global__ __launch_bounds__(256) void k_final(const double* __restrict__ ps,
                                               float* __restrict__ out) {
  __shared__ double ldsd[4][4];
  int tid = threadIdx.x;
  double s[4] = {0.0, 0.0, 0.0, 0.0};
  for (int i = tid; i < BLK_SUMS; i += 256) {
    s[0] += ps[i * 4 + 0];
    s[1] += ps[i * 4 + 1];
    s[2] += ps[i * 4 + 2];
    s[3] += ps[i * 4 + 3];
  }
  #pragma unroll
  for (int k = 0; k < 4; ++k)
    #pragma unroll
    for (int o = 32; o > 0; o >>= 1)
      s[k] += __shfl_xor(s[k], o, 64);
  if ((tid & 63) == 0) {
    #pragma unroll
    for (int k = 0; k < 4; ++k) ldsd[tid >> 6][k] = s[k];
  }
  __syncthreads();
  if (tid == 0) {
    double tot[4];
    #pragma unroll
    for (int k = 0; k < 4; ++k)
      tot[k] = ldsd[0][k] + ldsd[1][k] + ldsd[2][k] + ldsd[3][k];
    double wp = (tot[0] + 1.0) / (tot[1] + 1.0);
    double ws = (tot[2] + 1.0) / (tot[3] + 1.0);
    out[0] = (float)(1.0 - 2.0 * (wp * ws) / (wp + ws));
  }
}

} // namespace

extern "C" void kernel_launch(void* const* d_in, const int* in_sizes, int n_in,
                              void* d_out, int out_size, void* d_ws, size_t ws_size,
                              hipStream_t stream) {
  (void)in_sizes; (void)n_in; (void)out_size; (void)ws_size;
  const float* logits = (const float*)d_in[0];   // [B,2,D,H,W] f32
  const int* labels   = (const int*)d_in[1];     // [B,1,D,H,W] i32
  float* out = (float*)d_out;

  unsigned short* E2 = (unsigned short*)d_ws;      // final Euclidean d2 (u16, 0xFFFF=BIG)
  unsigned short* FZ = E2 + NT;                    // z-pass d2 (u16)
  unsigned char* DZ  = (unsigned char*)(FZ + NT);  // z-pass L1 (u8, 255=inf)
  unsigned char* D1  = DZ + NT;                    // 3D L1, capped 12 (u8)
  unsigned* SKELB = (unsigned*)(D1 + NT);          // NTW packed skel bits
  unsigned* PMAX  = SKELB + NTW;                   // 1024 per-tile masked maxes (u32 d2)
  double* PS      = (double*)(PMAX + 1024);        // 576x4 doubles (8B-aligned)

  k_bin0<<<1152, 256, 0, stream>>>(logits, labels, FZ, DZ);
  k_edtl1<<<1024, 256, 0, stream>>>(FZ, DZ, E2, D1);
  k_skelmax<<<1024, 256, 0, stream>>>(D1, E2, SKELB, PMAX);
  k_sums<<<576, 256, 0, stream>>>(E2, SKELB, PMAX, PS);
  k_final<<<1, 256, 0, stream>>>(PS, out);
}

// Round 4
// 118.858 us; speedup vs baseline: 1.2288x; 1.0400x over previous
//
#include <hip/hip_runtime.h>

namespace {

constexpr int Bn = 2;
constexpr int Dn = 64;
constexpr int Hn = 96;
constexpr int Wn = 96;
constexpr int HW = Hn * Wn;          // 9216
constexpr int S  = Dn * HW;          // 589824 per (vol,batch) slab
constexpr int NBS = Bn * S;          // 1179648
constexpr int NT  = 2 * NBS;         // 2359296 (slabs: predB0,predB1,truthB0,truthB1)
constexpr int WPP = HW / 32;         // 288 words per z-plane
constexpr int WPS = S / 32;          // 18432 words per slab
constexpr int NTW = NT / 32;         // 73728 packed words
constexpr float EPSf = 1e-7f;
constexpr int BLK_SUMS = NBS / 8 / 256;   // 576 (8 voxels per thread)
#define BIGF 1e12f                   // RN(1e12): exact all-foreground EDT value
constexpr int LINF = 1 << 20;

// ---- K1: binarize + z-EDT: d^2 as u16 (0xFFFF=BIG) + z-L1 u8 (255=inf) ----
__global__ __launch_bounds__(256) void k_bin0(const float* __restrict__ logits,
                                              const int* __restrict__ labels,
                                              unsigned short* __restrict__ FZ,
                                              unsigned char* __restrict__ DZ) {
  __shared__ unsigned bits[64];
  __shared__ unsigned zlo[32], zhi[32];
  int slab = blockIdx.x / 288;                 // 1152 blocks = 4 slabs x 288 groups
  int cg = blockIdx.x - slab * 288;
  int c0 = cg * 32;
  int tid = threadIdx.x;
  int lane = tid & 63;
  for (int t = tid; t < 2048; t += 256) {
    int zz = t >> 5;
    int col = t & 31;
    int s = zz * HW + c0 + col;
    bool v;
    if (slab < 2) {
      float l0 = logits[(slab * 2 + 0) * S + s];
      float l1 = logits[(slab * 2 + 1) * S + s];
      v = l1 > l0;                             // softmax(p1)>0.5 <=> l1>l0
    } else {
      v = labels[(slab - 2) * S + s] > 0;
    }
    unsigned long long m = __ballot(v);
    if (lane == 0)       bits[zz] = (unsigned)m;
    else if (lane == 32) bits[zz] = (unsigned)(m >> 32);
  }
  __syncthreads();
  if (tid < 64) {
    int col = tid & 31;
    int base = (tid < 32) ? 0 : 32;
    unsigned zw = 0u;
    #pragma unroll
    for (int j = 0; j < 32; ++j)
      zw |= (((bits[base + j] >> col) & 1u) ^ 1u) << j;
    if (tid < 32) zlo[col] = zw; else zhi[col] = zw;
  }
  __syncthreads();
  int col = tid & 31;
  int chunk = tid >> 5;
  int i0 = chunk * 8;
  unsigned long long Z = ((unsigned long long)zhi[col] << 32) | (unsigned long long)zlo[col];
  unsigned short* o = FZ + slab * S + c0 + col;
  unsigned char* o1 = DZ + slab * S + c0 + col;
  #pragma unroll
  for (int s = 0; s < 8; ++s) {
    int i = i0 + s;
    unsigned long long below = Z & ((2ull << i) - 1ull);
    unsigned long long above = Z >> i;
    unsigned short fv;
    unsigned char dv;
    if (below | above) {
      int ddn = below ? (i - (63 - __builtin_clzll(below))) : 99;
      int dup = above ? __builtin_ctzll(above) : 99;
      int d = ddn < dup ? ddn : dup;           // <= 63
      fv = (unsigned short)(d * d);
      dv = (unsigned char)d;
    } else {
      fv = 0xFFFFu;
      dv = 255;
    }
    o[i * HW] = fv;
    o1[i * HW] = dv;
  }
}

// ---- K2: windowed exact EDT (y,x) + L1 scans, quarter-plane per block ----
// Window bound: Euclid <= L1, so only |i-j| <= L1bound candidates can win;
// all small candidates are exact ints -> integer min == reference float min.
// E2 output is u16 d^2 (exact: finite best <= 253^2 = 64009), 0xFFFF = BIG.
__global__ __launch_bounds__(256) void k_edtl1(const unsigned short* __restrict__ FZ,
                                               const unsigned char* __restrict__ DZ,
                                               unsigned short* __restrict__ E2,
                                               unsigned char* __restrict__ D1) {
  __shared__ __align__(16) unsigned shm[8640]; // 34560 B
  unsigned short* fz = (unsigned short*)shm;          // 9216 u16 (plane d2z)
  unsigned char*  dz = (unsigned char*)(shm + 4608);  // 9216 u8  (plane L1z)
  unsigned char*  t1 = (unsigned char*)(shm + 6912);  // 24x96 u8 (zy-L1, tile)
  unsigned short* o1 = (unsigned short*)(shm + 7488); // 24x96 u16 (pass1 out)
  unsigned short* Afwd = (unsigned short*)shm;        // reuse fz after pass1
  unsigned short* Bbwd = (unsigned short*)(shm + 4608); // reuse dz after t1
  int slab = blockIdx.x >> 8;                  // 1024 = slab(4) x z(64) x q(4)
  int z = (blockIdx.x >> 2) & 63;
  int y0 = (blockIdx.x & 3) * 24;
  int tid = threadIdx.x;
  int pb = slab * S + z * HW;
  // stage plane (u16 d2z + u8 L1z), fully coalesced
  {
    const uint4* s4 = (const uint4*)(FZ + pb);
    uint4* d4 = (uint4*)fz;
    for (int t = tid; t < 1152; t += 256) d4[t] = s4[t];
    const uint4* s2 = (const uint4*)(DZ + pb);
    uint4* d2 = (uint4*)(shm + 4608);
    for (int t = tid; t < 576; t += 256) d2[t] = s2[t];
  }
  __syncthreads();
  // t1[rr][xx] = min_j |y-j| + dz[j][xx]  (uncapped; 255 = inf), tile rows only
  if (tid < 96) {
    int xx = tid;
    int P = LINF;
    int A[24];
    for (int j = 0; j < y0; ++j) {
      int v = dz[j * 96 + xx]; if (v == 255) v = LINF;
      P = min(P, v - j);
    }
    #pragma unroll
    for (int s = 0; s < 24; ++s) {
      int j = y0 + s;
      int v = dz[j * 96 + xx]; if (v == 255) v = LINF;
      P = min(P, v - j);
      A[s] = j + P;
    }
    int Sv = LINF;
    for (int j = 95; j >= y0 + 24; --j) {
      int v = dz[j * 96 + xx]; if (v == 255) v = LINF;
      Sv = min(Sv, v + j);
    }
    #pragma unroll
    for (int s = 23; s >= 0; --s) {
      int j = y0 + s;
      int v = dz[j * 96 + xx]; if (v == 255) v = LINF;
      Sv = min(Sv, v + j);
      int t = min(A[s], Sv - j);               // finite <= 158
      t1[s * 96 + xx] = (unsigned char)(t > 254 ? 255 : t);
    }
  }
  __syncthreads();
  // pass1 windowed: out1[y][xx] = min_{|y-j|<=t1} (y-j)^2 + fz[j][xx]
  for (int v = tid; v < 2304; v += 256) {
    int rr = v / 96;
    int xx = v - rr * 96;
    int y = y0 + rr;
    int r = t1[rr * 96 + xx];
    unsigned short res;
    if (r == 255) {
      res = 0xFFFFu;                           // whole (y,z) slice BIG -> RN(1e12)
    } else {
      int lo = y - r; if (lo < 0) lo = 0;
      int hi = y + r; if (hi > 95) hi = 95;
      int best = 1 << 30;
      for (int j = lo; j <= hi; ++j) {
        unsigned short f = fz[j * 96 + xx];
        if (f != 0xFFFFu) {
          int dd = y - j;
          best = min(best, dd * dd + (int)f);
        }
      }
      res = (unsigned short)best;              // <= t1^2 <= 24964; argmin in window
    }
    o1[rr * 96 + xx] = res;
  }
  __syncthreads();                             // fz free now
  // d1 row scans: Afwd/Bbwd halves of d1[rr][x] = min_j |x-j| + t1[rr][j]
  if (tid < 24) {                              // forward (wave 0)
    int rr = tid;
    int P = LINF;
    for (int j = 0; j < 96; ++j) {
      int v = t1[rr * 96 + j]; if (v == 255) v = LINF;
      P = min(P, v - j);
      int a = j + P;
      Afwd[rr * 96 + j] = (unsigned short)(a > 60000 ? 60000 : a);
    }
  }
  if (tid >= 64 && tid < 88) {                 // backward (wave 1)
    int rr = tid - 64;
    int Sv = LINF;
    for (int j = 95; j >= 0; --j) {
      int v = t1[rr * 96 + j]; if (v == 255) v = LINF;
      Sv = min(Sv, v + j);
      int b = Sv - j;                          // >= 0
      Bbwd[rr * 96 + j] = (unsigned short)(b > 60000 ? 60000 : b);
    }
  }
  __syncthreads();
  // pass2 windowed: E2 (u16 d^2) + capped-12 D1
  for (int v = tid; v < 2304; v += 256) {
    int rr = v / 96;
    int x = v - rr * 96;
    int d1v = min((int)Afwd[rr * 96 + x], (int)Bbwd[rr * 96 + x]);
    unsigned short oute;
    int d1c;
    if (d1v > 253) {                           // inf: whole plane BIG
      oute = 0xFFFFu;
      d1c = 12;
    } else {
      d1c = d1v < 12 ? d1v : 12;
      int lo = x - d1v; if (lo < 0) lo = 0;
      int hi = x + d1v; if (hi > 95) hi = 95;
      int best = 1 << 30;
      for (int j = lo; j <= hi; ++j) {
        unsigned short f = o1[rr * 96 + j];
        if (f != 0xFFFFu) {
          int dd = x - j;
          best = min(best, dd * dd + (int)f);
        }
      }
      oute = (unsigned short)best;             // <= d1^2 <= 64009 < 0xFFFF, exact
    }
    int gb = pb + (y0 + rr) * 96 + x;
    E2[gb] = oute;
    D1[gb] = (unsigned char)d1c;
  }
}

// ---- K3: skel = [d1 == max3x3x3(d1)] & [1<=d1<=11] + masked pmax (float) ----
__global__ __launch_bounds__(256) void k_skelmax(const unsigned char* __restrict__ D1,
                                                 const unsigned short* __restrict__ E2,
                                                 unsigned* __restrict__ SKELB,
                                                 float* __restrict__ pmax) {
  __shared__ unsigned char zm[26 * 96];
  __shared__ unsigned char cen[26 * 96];
  __shared__ float ldsf[4];
  int slab = blockIdx.x >> 8;
  int z = (blockIdx.x >> 2) & 63;
  int y0 = (blockIdx.x & 3) * 24;
  int tid = threadIdx.x;
  int pb = slab * S + z * HW;
  for (int t = tid; t < 2496; t += 256) {
    int rr = t / 96;
    int x = t - rr * 96;
    int yy = y0 - 1 + rr;
    unsigned char m = 0, cv = 0;
    if (yy >= 0 && yy < Hn) {
      int base = slab * S + yy * 96 + x;
      cv = D1[base + z * HW];
      m = cv;
      if (z > 0) { unsigned char a = D1[base + (z - 1) * HW]; m = m > a ? m : a; }
      if (z < Dn - 1) { unsigned char a = D1[base + (z + 1) * HW]; m = m > a ? m : a; }
    }
    zm[t] = m;
    cen[t] = cv;
  }
  __syncthreads();
  float mm = 0.0f;
  int wbase = slab * WPS + z * WPP + y0 * 3;
  int lane = tid & 63;
  #pragma unroll
  for (int round = 0; round < 9; ++round) {
    int v = round * 256 + tid;
    int rr = v / 96;
    int x = v - rr * 96;
    int b1 = rr * 96 + x;
    unsigned char mx = zm[b1];
    { unsigned char a = zm[b1 + 96]; mx = mx > a ? mx : a; }
    { unsigned char a = zm[b1 + 192]; mx = mx > a ? mx : a; }
    if (x > 0) {
      unsigned char a0 = zm[b1 - 1], a1 = zm[b1 + 95], a2 = zm[b1 + 191];
      unsigned char a = a0 > a1 ? a0 : a1; a = a > a2 ? a : a2;
      mx = mx > a ? mx : a;
    }
    if (x < Wn - 1) {
      unsigned char a0 = zm[b1 + 1], a1 = zm[b1 + 97], a2 = zm[b1 + 193];
      unsigned char a = a0 > a1 ? a0 : a1; a = a > a2 ? a : a2;
      mx = mx > a ? mx : a;
    }
    unsigned char d1 = cen[b1 + 96];
    bool sk = (d1 == mx) && (d1 >= 1) && (d1 <= 11);
    unsigned long long bal = __ballot(sk);
    if (lane == 0)       SKELB[wbase + (v >> 5)] = (unsigned)bal;
    else if (lane == 32) SKELB[wbase + (v >> 5)] = (unsigned)(bal >> 32);
    if (sk) {
      unsigned e = E2[pb + (y0 + rr) * 96 + x]; // finite at skel voxels, <= 64009
      mm = fmaxf(mm, (float)e);                // exact int -> float
    }
  }
  #pragma unroll
  for (int o = 32; o > 0; o >>= 1) mm = fmaxf(mm, __shfl_xor(mm, o, 64));
  if (lane == 0) ldsf[tid >> 6] = mm;
  __syncthreads();
  if (tid == 0)
    pmax[blockIdx.x] = fmaxf(fmaxf(ldsf[0], ldsf[1]), fmaxf(ldsf[2], ldsf[3]));
}

// ---- K4: sums, 8 voxels/thread (576 blocks), plain partial stores ----
__global__ __launch_bounds__(256) void k_sums(const unsigned short* __restrict__ E2,
                                              const unsigned* __restrict__ skel,
                                              const float* __restrict__ pmax,
                                              double* __restrict__ ps) {
  __shared__ float lmax[4];
  __shared__ double ldsd[4][4];
  int tid = threadIdx.x;
  {
    int wave = tid >> 6, lane = tid & 63;
    const float* pw = pmax + wave * 256;
    float v = fmaxf(fmaxf(pw[lane], pw[lane + 64]),
                    fmaxf(pw[lane + 128], pw[lane + 192]));
    #pragma unroll
    for (int o = 32; o > 0; o >>= 1) v = fmaxf(v, __shfl_xor(v, o, 64));
    if (lane == 0) lmax[wave] = v;
  }
  __syncthreads();
  int q = blockIdx.x * 256 + tid;
  int idx0 = q * 8;
  int b = idx0 / S;
  float rmax_p = sqrtf(lmax[b]);
  float rmax_t = sqrtf(lmax[2 + b]);
  uint4 dp4 = ((const uint4*)E2)[q];
  uint4 dt4 = ((const uint4*)E2)[q + NBS / 8];
  unsigned spw = (skel[idx0 >> 5] >> (idx0 & 31)) & 0xFFu;
  unsigned stw = (skel[(NBS + idx0) >> 5] >> (idx0 & 31)) & 0xFFu;
  const unsigned short* dp = (const unsigned short*)&dp4;
  const unsigned short* dt = (const unsigned short*)&dt4;
  double acc[4] = {0.0, 0.0, 0.0, 0.0};
  #pragma unroll
  for (int s = 0; s < 8; ++s) {
    unsigned pv = dp[s];
    unsigned tv = dt[s];
    float pd2 = (pv == 0xFFFFu) ? BIGF : (float)pv;
    float td2 = (tv == 0xFFFFu) ? BIGF : (float)tv;
    float dist_p = sqrtf(pd2);
    float dist_t = sqrtf(td2);
    bool sp = (spw >> s) & 1u;
    bool st = (stw >> s) & 1u;
    float q_vp = (rmax_p > 0.0f) ? dist_p / rmax_p : dist_p;
    float q_vl = (rmax_t > 0.0f) ? dist_t / rmax_t : dist_t;
    float q_spvp = sp ? q_vp : 0.0f;
    float q_slvl = st ? q_vl : 0.0f;
    float q_sp = sp ? (1.0f + EPSf) / (q_spvp * q_spvp + EPSf) : 0.0f;
    float q_sl = st ? (1.0f + EPSf) / (q_slvl * q_slvl + EPSf) : 0.0f;
    acc[0] += (double)(q_sp * q_vl);
    acc[1] += (double)(((q_spvp != 0.0f) && (q_slvl == 0.0f)) ? q_spvp * q_sp
                                                              : q_slvl * q_sp);
    acc[2] += (double)(q_sl * q_vp);
    acc[3] += (double)(((q_slvl != 0.0f) && (q_spvp == 0.0f)) ? q_slvl * q_sl
                                                              : q_spvp * q_sl);
  }
  #pragma unroll
  for (int k = 0; k < 4; ++k)
    #pragma unroll
    for (int o = 32; o > 0; o >>= 1)
      acc[k] += __shfl_xor(acc[k], o, 64);
  if ((tid & 63) == 0) {
    #pragma unroll
    for (int k = 0; k < 4; ++k) ldsd[tid >> 6][k] = acc[k];
  }
  __syncthreads();
  if (tid == 0) {
    #pragma unroll
    for (int k = 0; k < 4; ++k)
      ps[blockIdx.x * 4 + k] = ldsd[0][k] + ldsd[1][k] + ldsd[2][k] + ldsd[3][k];
  }
}

// ---- K5: final reduce + loss ----
__global__ __launch_bounds__(256) void k_final(const double* __restrict__ ps,
                                               float* __restrict__ out) {
  __shared__ double ldsd[4][4];
  int tid = threadIdx.x;
  double s[4] = {0.0, 0.0, 0.0, 0.0};
  for (int i = tid; i < BLK_SUMS; i += 256) {
    s[0] += ps[i * 4 + 0];
    s[1] += ps[i * 4 + 1];
    s[2] += ps[i * 4 + 2];
    s[3] += ps[i * 4 + 3];
  }
  #pragma unroll
  for (int k = 0; k < 4; ++k)
    #pragma unroll
    for (int o = 32; o > 0; o >>= 1)
      s[k] += __shfl_xor(s[k], o, 64);
  if ((tid & 63) == 0) {
    #pragma unroll
    for (int k = 0; k < 4; ++k) ldsd[tid >> 6][k] = s[k];
  }
  __syncthreads();
  if (tid == 0) {
    double tot[4];
    #pragma unroll
    for (int k = 0; k < 4; ++k)
      tot[k] = ldsd[0][k] + ldsd[1][k] + ldsd[2][k] + ldsd[3][k];
    double wp = (tot[0] + 1.0) / (tot[1] + 1.0);
    double ws = (tot[2] + 1.0) / (tot[3] + 1.0);
    out[0] = (float)(1.0 - 2.0 * (wp * ws) / (wp + ws));
  }
}

} // namespace

extern "C" void kernel_launch(void* const* d_in, const int* in_sizes, int n_in,
                              void* d_out, int out_size, void* d_ws, size_t ws_size,
                              hipStream_t stream) {
  (void)in_sizes; (void)n_in; (void)out_size; (void)ws_size;
  const float* logits = (const float*)d_in[0];   // [B,2,D,H,W] f32
  const int* labels   = (const int*)d_in[1];     // [B,1,D,H,W] i32
  float* out = (float*)d_out;

  unsigned short* E2 = (unsigned short*)d_ws;      // final Euclidean d2 (u16, 0xFFFF=BIG)
  unsigned short* FZ = E2 + NT;                    // z-pass d2 (u16)
  unsigned char* DZ  = (unsigned char*)(FZ + NT);  // z-pass L1 (u8, 255=inf)
  unsigned char* D1  = DZ + NT;                    // 3D L1, capped 12 (u8)
  unsigned* SKELB = (unsigned*)(D1 + NT);          // NTW packed skel bits
  float* PMAX  = (float*)(SKELB + NTW);            // 1024 per-tile masked maxes
  double* PS   = (double*)(PMAX + 1024);           // 576x4 doubles (8B-aligned)

  k_bin0<<<1152, 256, 0, stream>>>(logits, labels, FZ, DZ);
  k_edtl1<<<1024, 256, 0, stream>>>(FZ, DZ, E2, D1);
  k_skelmax<<<1024, 256, 0, stream>>>(D1, E2, SKELB, PMAX);
  k_sums<<<576, 256, 0, stream>>>(E2, SKELB, PMAX, PS);
  k_final<<<1, 256, 0, stream>>>(PS, out);
}